// Round 1
// baseline (2297.247 us; speedup 1.0000x reference)
//
#include <hip/hip_runtime.h>
#include <math.h>

// Model dims
#define NB 2
#define LSEQ 1024
#define DM 512
#define FFD 2048
#define NHEAD 8
#define DKH 64
#define NLAYER 4
#define VOCAB 8000
#define NCHUNK 16   // L / 64
#define NROWS (NB * LSEQ)   // 2048

#define OP_NONE 0
#define OP_ELU1 1
#define OP_GELU 2

// ---------------------------------------------------------------------------
// Generic fp32 tiled GEMM: C = op(A @ W + bias) + res
// A: (M,K) row-major, W: (K,N) row-major. 64x64 tile, 256 threads, 4x4/thread.
// M%64==0, N%64==0, K%16==0 (holds for all shapes here).
// ---------------------------------------------------------------------------
__global__ __launch_bounds__(256) void gemm_ep(
    const float* __restrict__ A, const float* __restrict__ W,
    const float* __restrict__ bias, const float* __restrict__ res,
    float* __restrict__ C, int M, int N, int K, int op)
{
    __shared__ float As[16][68];   // [k][m], stride 68 floats keeps 16B align
    __shared__ float Bs[16][68];   // [k][n]
    const int tid = threadIdx.x;
    const int tx = tid & 15;        // n-dir
    const int ty = tid >> 4;        // m-dir
    const int bm = blockIdx.y * 64;
    const int bn = blockIdx.x * 64;

    const int mA = tid >> 2;            // 0..63
    const int kA = (tid & 3) << 2;      // 0,4,8,12
    const int kB = tid >> 4;            // 0..15
    const int nB = (tid & 15) << 2;     // 0..60

    float acc[4][4] = {};

    for (int k0 = 0; k0 < K; k0 += 16) {
        const float4 a4 = *(const float4*)(A + (size_t)(bm + mA) * K + k0 + kA);
        As[kA + 0][mA] = a4.x; As[kA + 1][mA] = a4.y;
        As[kA + 2][mA] = a4.z; As[kA + 3][mA] = a4.w;
        const float4 b4 = *(const float4*)(W + (size_t)(k0 + kB) * N + bn + nB);
        Bs[kB][nB + 0] = b4.x; Bs[kB][nB + 1] = b4.y;
        Bs[kB][nB + 2] = b4.z; Bs[kB][nB + 3] = b4.w;
        __syncthreads();
        #pragma unroll
        for (int k = 0; k < 16; ++k) {
            float a[4], b[4];
            #pragma unroll
            for (int i = 0; i < 4; ++i) a[i] = As[k][ty * 4 + i];
            #pragma unroll
            for (int j = 0; j < 4; ++j) b[j] = Bs[k][tx * 4 + j];
            #pragma unroll
            for (int i = 0; i < 4; ++i)
                #pragma unroll
                for (int j = 0; j < 4; ++j)
                    acc[i][j] = fmaf(a[i], b[j], acc[i][j]);
        }
        __syncthreads();
    }

    #pragma unroll
    for (int i = 0; i < 4; ++i) {
        const int row = bm + ty * 4 + i;
        #pragma unroll
        for (int j = 0; j < 4; ++j) {
            const int col = bn + tx * 4 + j;
            float v = acc[i][j] + bias[col];
            if (op == OP_ELU1)      v = (v > 0.f) ? v + 1.f : expf(v);
            else if (op == OP_GELU) v = 0.5f * v * (1.f + erff(v * 0.70710678118654752f));
            if (res) v += res[(size_t)row * N + col];
            C[(size_t)row * N + col] = v;
        }
    }
}

// ---------------------------------------------------------------------------
// Embedding: combine image GEMM result + pos-enc, text embedding + pos-enc.
// gI = x_img @ W_ei + b_ei (precomputed). One block per (n,l) row.
// ---------------------------------------------------------------------------
__global__ __launch_bounds__(256) void embed_k(
    const float* __restrict__ gI, const int* __restrict__ xt,
    const float* __restrict__ emb,
    const float* __restrict__ mi, const float* __restrict__ mt,
    const float* __restrict__ pr, const float* __restrict__ pc,
    const float* __restrict__ pt, float* __restrict__ X)
{
    const int row = blockIdx.x;  // n*L + l
    const float prv = pr[row], pcv = pc[row], ptv = pt[row];
    const float miv = mi[row], mtv = mt[row];
    const int tok = xt[row];
    const float LOG1E4 = 9.2103403719761836f;
    const float LI127 = LOG1E4 / 127.f;   // pos_enc over 256 ch -> num=128
    const float LI255 = LOG1E4 / 255.f;   // pos_enc over 512 ch -> num=256

    for (int d = threadIdx.x; d < DM; d += 256) {
        float ip;
        if (d < 128)       ip = sinf(prv * expf(-(float)d * LI127));
        else if (d < 256)  ip = cosf(prv * expf(-(float)(d - 128) * LI127));
        else if (d < 384)  ip = sinf(pcv * expf(-(float)(d - 256) * LI127));
        else               ip = cosf(pcv * expf(-(float)(d - 384) * LI127));
        float tp;
        if (d < 256) tp = sinf(ptv * expf(-(float)d * LI255));
        else         tp = cosf(ptv * expf(-(float)(d - 256) * LI255));
        const float v = miv * (gI[(size_t)row * DM + d] + ip)
                      + mtv * (emb[(size_t)tok * DM + d] + tp);
        X[(size_t)row * DM + d] = v;
    }
}

// ---------------------------------------------------------------------------
// LayerNorm over last dim (512). One block per row.
// ---------------------------------------------------------------------------
__global__ __launch_bounds__(256) void ln_k(
    const float* __restrict__ in, const float* __restrict__ g,
    const float* __restrict__ b, float* __restrict__ out)
{
    const int row = blockIdx.x;
    const int tid = threadIdx.x;
    const float* x = in + (size_t)row * DM;
    const float x0 = x[tid], x1 = x[tid + 256];
    __shared__ float red[256];

    red[tid] = x0 + x1;
    __syncthreads();
    for (int off = 128; off > 0; off >>= 1) {
        if (tid < off) red[tid] += red[tid + off];
        __syncthreads();
    }
    const float mean = red[0] / (float)DM;
    __syncthreads();
    const float d0 = x0 - mean, d1 = x1 - mean;
    red[tid] = d0 * d0 + d1 * d1;
    __syncthreads();
    for (int off = 128; off > 0; off >>= 1) {
        if (tid < off) red[tid] += red[tid + off];
        __syncthreads();
    }
    const float var = red[0] / (float)DM;
    const float rstd = rsqrtf(var + 1e-5f);
    out[(size_t)row * DM + tid]       = d0 * rstd * g[tid] + b[tid];
    out[(size_t)row * DM + tid + 256] = d1 * rstd * g[tid + 256] + b[tid + 256];
}

// ---------------------------------------------------------------------------
// Linear attention, chunked scan. State per (n,h): 64x64 KV matrix + 64 ksum.
// Pass 1: per-chunk sums. Grid (chunk, head, batch), 256 thr.
// Thread t owns state column e=t&63, rows [16*(t>>6), +16).
// ---------------------------------------------------------------------------
__global__ __launch_bounds__(256) void attn_chunk_sum(
    const float* __restrict__ K, const float* __restrict__ V,
    float* __restrict__ S, float* __restrict__ ks)
{
    const int c = blockIdx.x, h = blockIdx.y, n = blockIdx.z;
    const int tid = threadIdx.x;
    const int e = tid & 63, dq = tid >> 6;
    __shared__ float sK[64], sV[64];
    float s[16] = {};
    float kacc = 0.f;
    for (int l = c * 64; l < c * 64 + 64; ++l) {
        const size_t base = ((size_t)(n * LSEQ + l)) * DM + h * DKH;
        __syncthreads();
        if (tid < 64) {
            const float kv = K[base + tid];
            sK[tid] = kv; kacc += kv;
            sV[tid] = V[base + tid];
        }
        __syncthreads();
        const float vv = sV[e];
        #pragma unroll
        for (int i = 0; i < 16; ++i) s[i] = fmaf(sK[dq * 16 + i], vv, s[i]);
    }
    const size_t sb = (((size_t)(n * NHEAD + h)) * NCHUNK + c) * 4096;
    #pragma unroll
    for (int i = 0; i < 16; ++i) S[sb + (size_t)(dq * 16 + i) * 64 + e] = s[i];
    if (tid < 64) kacc = kacc, ks[(((size_t)(n * NHEAD + h)) * NCHUNK + c) * 64 + tid] = kacc;
}

// Pass 2: exclusive prefix over the 16 chunks, in-place. Grid = N*H blocks.
__global__ __launch_bounds__(256) void attn_prefix(
    float* __restrict__ S, float* __restrict__ ks)
{
    const int nh = blockIdx.x;
    const int tid = threadIdx.x;
    float run[16];
    #pragma unroll
    for (int i = 0; i < 16; ++i) run[i] = 0.f;
    float krun = 0.f;
    for (int c = 0; c < NCHUNK; ++c) {
        const size_t sb = (((size_t)nh) * NCHUNK + c) * 4096;
        #pragma unroll
        for (int i = 0; i < 16; ++i) {
            const float t = S[sb + tid * 16 + i];
            S[sb + tid * 16 + i] = run[i];
            run[i] += t;
        }
        if (tid < 64) {
            const size_t kb = (((size_t)nh) * NCHUNK + c) * 64;
            const float t = ks[kb + tid];
            ks[kb + tid] = krun;
            krun += t;
        }
    }
}

// Pass 3: in-chunk sequential scan starting from the prefix state.
// out[l,e] = (Q_l . KV_l[:,e]) / (Q_l . ksum_l + eps), inclusive update.
__global__ __launch_bounds__(256) void attn_scan(
    const float* __restrict__ Q, const float* __restrict__ K,
    const float* __restrict__ V, const float* __restrict__ S,
    const float* __restrict__ ks, float* __restrict__ O)
{
    const int c = blockIdx.x, h = blockIdx.y, n = blockIdx.z;
    const int tid = threadIdx.x;
    const int e = tid & 63, dq = tid >> 6;
    __shared__ float sK[64], sV[64], sQ[64], sks[64], part[256];

    const size_t sb = (((size_t)(n * NHEAD + h)) * NCHUNK + c) * 4096;
    float s[16];
    #pragma unroll
    for (int i = 0; i < 16; ++i) s[i] = S[sb + (size_t)(dq * 16 + i) * 64 + e];
    if (tid < 64) sks[tid] = ks[(((size_t)(n * NHEAD + h)) * NCHUNK + c) * 64 + tid];

    for (int l = c * 64; l < c * 64 + 64; ++l) {
        const size_t base = ((size_t)(n * LSEQ + l)) * DM + h * DKH;
        __syncthreads();
        if (tid < 64) {
            sK[tid] = K[base + tid];
            sV[tid] = V[base + tid];
            sQ[tid] = Q[base + tid];
        }
        __syncthreads();
        const float vv = sV[e];
        float p = 0.f;
        #pragma unroll
        for (int i = 0; i < 16; ++i) {
            s[i] = fmaf(sK[dq * 16 + i], vv, s[i]);
            p = fmaf(sQ[dq * 16 + i], s[i], p);
        }
        part[tid] = p;
        if (tid < 64) sks[tid] += sK[tid];
        __syncthreads();
        if (tid < 64) {
            const float o = part[tid] + part[tid + 64] + part[tid + 128] + part[tid + 192];
            float zp = sQ[tid] * sks[tid];
            #pragma unroll
            for (int off = 32; off > 0; off >>= 1) zp += __shfl_down(zp, off);
            const float z = __shfl(zp, 0);
            O[base + tid] = o / (z + 1e-6f);
        }
    }
}

// ---------------------------------------------------------------------------
extern "C" void kernel_launch(void* const* d_in, const int* in_sizes, int n_in,
                              void* d_out, int out_size, void* d_ws, size_t ws_size,
                              hipStream_t stream)
{
    const float* x_img   = (const float*)d_in[0];
    const int*   x_txt   = (const int*)  d_in[1];
    const float* mask_i  = (const float*)d_in[2];
    const float* mask_t  = (const float*)d_in[3];
    const float* pos_r   = (const float*)d_in[4];
    const float* pos_c   = (const float*)d_in[5];
    const float* pos_t   = (const float*)d_in[6];
    const float* W_ei    = (const float*)d_in[7];
    const float* b_ei    = (const float*)d_in[8];
    const float* emb_txt = (const float*)d_in[9];
    const float* Wq      = (const float*)d_in[10];
    const float* bq      = (const float*)d_in[11];
    const float* Wk      = (const float*)d_in[12];
    const float* bk      = (const float*)d_in[13];
    const float* Wv      = (const float*)d_in[14];
    const float* bv      = (const float*)d_in[15];
    const float* Wo      = (const float*)d_in[16];
    const float* bo      = (const float*)d_in[17];
    const float* W1      = (const float*)d_in[18];
    const float* b1      = (const float*)d_in[19];
    const float* W2      = (const float*)d_in[20];
    const float* b2      = (const float*)d_in[21];
    const float* ln1_s   = (const float*)d_in[22];
    const float* ln1_b   = (const float*)d_in[23];
    const float* ln2_s   = (const float*)d_in[24];
    const float* ln2_b   = (const float*)d_in[25];
    const float* W_pi    = (const float*)d_in[26];
    const float* b_pi    = (const float*)d_in[27];
    const float* W_pt    = (const float*)d_in[28];
    const float* b_pt    = (const float*)d_in[29];

    float* ws = (float*)d_ws;
    const size_t M1 = 1048576;           // N*L*D floats
    float* Xb  = ws;                     // activations (carried between layers)
    float* Qb  = ws + 1 * M1;
    float* Kb  = ws + 2 * M1;
    float* Vb  = ws + 3 * M1;
    float* Ab  = ws + 4 * M1;            // attn out / embed gemm scratch
    float* Tb  = ws + 5 * M1;            // FF intermediate (4M floats)
    float* Yb  = ws + 9 * M1;            // residual-sum scratch
    float* Sb  = ws + 10 * M1;           // chunk KV sums -> prefixes (1M floats)
    float* ksb = ws + 11 * M1;           // chunk ksum    -> prefixes (16K floats)

    const dim3 blk(256);
    const dim3 gD(DM / 64, NROWS / 64);      // N=512 gemms
    const dim3 gF(FFD / 64, NROWS / 64);     // N=2048 gemm
    const dim3 gV(VOCAB / 64, NROWS / 64);   // N=8000 gemm
    const dim3 gAttn(NCHUNK, NHEAD, NB);

    // Embedding
    gemm_ep<<<gD, blk, 0, stream>>>(x_img, W_ei, b_ei, nullptr, Ab,
                                    NROWS, DM, DM, OP_NONE);
    embed_k<<<NROWS, blk, 0, stream>>>(Ab, x_txt, emb_txt, mask_i, mask_t,
                                       pos_r, pos_c, pos_t, Xb);

    for (int i = 0; i < NLAYER; ++i) {
        const float* Wq_i = Wq + (size_t)i * DM * DM;
        const float* Wk_i = Wk + (size_t)i * DM * DM;
        const float* Wv_i = Wv + (size_t)i * DM * DM;
        const float* Wo_i = Wo + (size_t)i * DM * DM;
        const float* W1_i = W1 + (size_t)i * DM * FFD;
        const float* W2_i = W2 + (size_t)i * FFD * DM;
        const float* bq_i = bq + (size_t)i * DM;
        const float* bk_i = bk + (size_t)i * DM;
        const float* bv_i = bv + (size_t)i * DM;
        const float* bo_i = bo + (size_t)i * DM;
        const float* b1_i = b1 + (size_t)i * FFD;
        const float* b2_i = b2 + (size_t)i * DM;

        // Q/K get the elu+1 feature map fused into the GEMM epilogue
        gemm_ep<<<gD, blk, 0, stream>>>(Xb, Wq_i, bq_i, nullptr, Qb,
                                        NROWS, DM, DM, OP_ELU1);
        gemm_ep<<<gD, blk, 0, stream>>>(Xb, Wk_i, bk_i, nullptr, Kb,
                                        NROWS, DM, DM, OP_ELU1);
        gemm_ep<<<gD, blk, 0, stream>>>(Xb, Wv_i, bv_i, nullptr, Vb,
                                        NROWS, DM, DM, OP_NONE);

        attn_chunk_sum<<<gAttn, blk, 0, stream>>>(Kb, Vb, Sb, ksb);
        attn_prefix<<<NB * NHEAD, blk, 0, stream>>>(Sb, ksb);
        attn_scan<<<gAttn, blk, 0, stream>>>(Qb, Kb, Vb, Sb, ksb, Ab);

        // out proj + residual, then LN1
        gemm_ep<<<gD, blk, 0, stream>>>(Ab, Wo_i, bo_i, Xb, Yb,
                                        NROWS, DM, DM, OP_NONE);
        ln_k<<<NROWS, blk, 0, stream>>>(Yb, ln1_s + (size_t)i * DM,
                                        ln1_b + (size_t)i * DM, Xb);

        // FF: gelu(X@W1+b1)@W2 + b2 + X, then LN2
        gemm_ep<<<gF, blk, 0, stream>>>(Xb, W1_i, b1_i, nullptr, Tb,
                                        NROWS, FFD, DM, OP_GELU);
        gemm_ep<<<gD, blk, 0, stream>>>(Tb, W2_i, b2_i, Xb, Yb,
                                        NROWS, DM, FFD, OP_NONE);
        ln_k<<<NROWS, blk, 0, stream>>>(Yb, ln2_s + (size_t)i * DM,
                                        ln2_b + (size_t)i * DM, Xb);
    }

    // Heads
    float* out = (float*)d_out;
    gemm_ep<<<gD, blk, 0, stream>>>(Xb, W_pi, b_pi, nullptr, out,
                                    NROWS, DM, DM, OP_NONE);
    gemm_ep<<<gV, blk, 0, stream>>>(Xb, W_pt, b_pt, nullptr, out + M1,
                                    NROWS, VOCAB, DM, OP_NONE);
}

// Round 2
// 1145.555 us; speedup vs baseline: 2.0054x; 2.0054x over previous
//
#include <hip/hip_runtime.h>
#include <hip/hip_bf16.h>
#include <math.h>

// Model dims
#define NB 2
#define LSEQ 1024
#define DM 512
#define FFD 2048
#define NHEAD 8
#define DKH 64
#define NLAYER 4
#define VOCAB 8000
#define VPAD 8064           // vocab padded to /128
#define NCHUNK 16           // L / 64
#define NROWS (NB * LSEQ)   // 2048
#define QS 1536             // fused QKV row stride

#define OP_NONE 0
#define OP_ELU1 1
#define OP_GELU 2
#define OP_QKV  3   // elu+1 for col<1024 (Q,K), none for V

typedef __attribute__((ext_vector_type(8))) short short8;
typedef __attribute__((ext_vector_type(4))) float f32x4;
typedef __hip_bfloat16 bf16;

// ---------------------------------------------------------------------------
// Transpose-cast: src (K,N) fp32 row-major  ->  dst (Npad,K) bf16 row-major.
// Rows n>=N are zero-filled. blockIdx.z batches layers.
// ---------------------------------------------------------------------------
__global__ __launch_bounds__(256) void cast_t(
    const float* __restrict__ src, bf16* __restrict__ dst,
    int K, int N, size_t sStride, size_t dStride)
{
    __shared__ float tile[32][33];
    const int z = blockIdx.z;
    const float* s = src + (size_t)z * sStride;
    bf16* d = dst + (size_t)z * dStride;
    const int n0 = blockIdx.x * 32;
    const int k0 = blockIdx.y * 32;
    const int tx = threadIdx.x & 31;
    const int ty = threadIdx.x >> 5;   // 0..7
    #pragma unroll
    for (int i = 0; i < 4; ++i) {
        const int k = k0 + ty + 8 * i;
        const int n = n0 + tx;
        tile[ty + 8 * i][tx] = (n < N) ? s[(size_t)k * N + n] : 0.f;
    }
    __syncthreads();
    #pragma unroll
    for (int i = 0; i < 4; ++i) {
        const int n = n0 + ty + 8 * i;
        d[(size_t)n * K + k0 + tx] = __float2bfloat16(tile[tx][ty + 8 * i]);
    }
}

// Elementwise fp32 -> bf16 (layout preserved)
__global__ __launch_bounds__(256) void cast_e(
    const float* __restrict__ src, bf16* __restrict__ dst, int n4)
{
    const int i = blockIdx.x * 256 + threadIdx.x;
    if (i < n4) {
        const float4 v = *(const float4*)(src + (size_t)i * 4);
        dst[(size_t)i * 4 + 0] = __float2bfloat16(v.x);
        dst[(size_t)i * 4 + 1] = __float2bfloat16(v.y);
        dst[(size_t)i * 4 + 2] = __float2bfloat16(v.z);
        dst[(size_t)i * 4 + 3] = __float2bfloat16(v.w);
    }
}

// Build fused QKV bias (NL,1536)
__global__ __launch_bounds__(256) void qkv_bias_k(
    const float* __restrict__ bq, const float* __restrict__ bk,
    const float* __restrict__ bv, float* __restrict__ out)
{
    const int z = blockIdx.x;
    for (int j = threadIdx.x; j < QS; j += 256) {
        float v;
        if (j < 512)       v = bq[z * DM + j];
        else if (j < 1024) v = bk[z * DM + j - 512];
        else               v = bv[z * DM + j - 1024];
        out[z * QS + j] = v;
    }
}

// ---------------------------------------------------------------------------
// bf16 MFMA GEMM: C = op(A @ B + bias) [+ res]
// A (M,K) bf16 row-major; Bt (Npad,K) bf16 row-major (i.e. B transposed).
// Npad = gridDim.x*BN. Stores to outF (fp32) and/or outH (bf16), both
// (M,Nout) row-major, predicated on col<Nout. 256 threads = 4 waves (2x2).
// ---------------------------------------------------------------------------
template<int BM, int BN>
__global__ __launch_bounds__(256) void gemm16(
    const bf16* __restrict__ A, const bf16* __restrict__ Bt,
    const float* __restrict__ bias, const float* __restrict__ res,
    float* __restrict__ outF, bf16* __restrict__ outH,
    int M, int K, int Nout, int op)
{
    constexpr int WM = BM / 2, WN = BN / 2, MI = WM / 16, NI = WN / 16;
    __shared__ bf16 As[BM * 32];
    __shared__ bf16 Bs[BN * 32];
    const int tid = threadIdx.x;
    const int lane = tid & 63;
    const int wave = tid >> 6;
    const int wm = (wave >> 1) * WM, wn = (wave & 1) * WN;
    const int bm = blockIdx.y * BM, bn = blockIdx.x * BN;
    const int l16 = lane & 15, quad = lane >> 4;

    const int rA = tid >> 2;            // staged row 0..63 (+64 per issue)
    const int c8 = (tid & 3) << 3;      // bf16 col offset within BK=32

    f32x4 acc[MI][NI];
    #pragma unroll
    for (int i = 0; i < MI; ++i)
        #pragma unroll
        for (int j = 0; j < NI; ++j) acc[i][j] = (f32x4){0.f, 0.f, 0.f, 0.f};

    const bf16* gA = A  + (size_t)(bm + rA) * K + c8;
    const bf16* gB = Bt + (size_t)(bn + rA) * K + c8;
    const int ldsWaveOff = wave * 1024;   // 64 lanes * 16B

    for (int k0 = 0; k0 < K; k0 += 32) {
        __syncthreads();
        #pragma unroll
        for (int i = 0; i < BM / 64; ++i)
            __builtin_amdgcn_global_load_lds(
                (const __attribute__((address_space(1))) void*)(gA + (size_t)i * 64 * K + k0),
                (__attribute__((address_space(3))) void*)((char*)As + i * 4096 + ldsWaveOff),
                16, 0, 0);
        #pragma unroll
        for (int i = 0; i < BN / 64; ++i)
            __builtin_amdgcn_global_load_lds(
                (const __attribute__((address_space(1))) void*)(gB + (size_t)i * 64 * K + k0),
                (__attribute__((address_space(3))) void*)((char*)Bs + i * 4096 + ldsWaveOff),
                16, 0, 0);
        __syncthreads();
        short8 a[MI], b[NI];
        #pragma unroll
        for (int i = 0; i < MI; ++i)
            a[i] = *(const short8*)(As + (size_t)(wm + i * 16 + l16) * 32 + quad * 8);
        #pragma unroll
        for (int j = 0; j < NI; ++j)
            b[j] = *(const short8*)(Bs + (size_t)(wn + j * 16 + l16) * 32 + quad * 8);
        #pragma unroll
        for (int i = 0; i < MI; ++i)
            #pragma unroll
            for (int j = 0; j < NI; ++j)
                acc[i][j] = __builtin_amdgcn_mfma_f32_16x16x32_bf16(
                    a[i], b[j], acc[i][j], 0, 0, 0);
    }

    #pragma unroll
    for (int j = 0; j < NI; ++j) {
        const int col = bn + wn + j * 16 + l16;
        const bool cok = (col < Nout);
        const float bz = cok ? bias[col] : 0.f;
        #pragma unroll
        for (int i = 0; i < MI; ++i) {
            #pragma unroll
            for (int r = 0; r < 4; ++r) {
                const int row = bm + wm + i * 16 + quad * 4 + r;
                float v = acc[i][j][r] + bz;
                if (op == OP_ELU1)      v = (v > 0.f) ? v + 1.f : expf(v);
                else if (op == OP_GELU) v = 0.5f * v * (1.f + erff(v * 0.70710678118654752f));
                else if (op == OP_QKV && col < 1024) v = (v > 0.f) ? v + 1.f : expf(v);
                if (cok) {
                    if (res)  v += res[(size_t)row * Nout + col];
                    if (outF) outF[(size_t)row * Nout + col] = v;
                    if (outH) outH[(size_t)row * Nout + col] = __float2bfloat16(v);
                }
            }
        }
    }
}

// ---------------------------------------------------------------------------
// Embedding combine. gI = x_img @ W_ei + b_ei (precomputed fp32).
// ---------------------------------------------------------------------------
__global__ __launch_bounds__(256) void embed_k(
    const float* __restrict__ gI, const int* __restrict__ xt,
    const float* __restrict__ emb,
    const float* __restrict__ mi, const float* __restrict__ mt,
    const float* __restrict__ pr, const float* __restrict__ pc,
    const float* __restrict__ pt, float* __restrict__ X, bf16* __restrict__ Xh)
{
    const int row = blockIdx.x;
    const float prv = pr[row], pcv = pc[row], ptv = pt[row];
    const float miv = mi[row], mtv = mt[row];
    const int tok = xt[row];
    const float LOG1E4 = 9.2103403719761836f;
    const float LI127 = LOG1E4 / 127.f;
    const float LI255 = LOG1E4 / 255.f;

    for (int d = threadIdx.x; d < DM; d += 256) {
        float ip;
        if (d < 128)       ip = sinf(prv * expf(-(float)d * LI127));
        else if (d < 256)  ip = cosf(prv * expf(-(float)(d - 128) * LI127));
        else if (d < 384)  ip = sinf(pcv * expf(-(float)(d - 256) * LI127));
        else               ip = cosf(pcv * expf(-(float)(d - 384) * LI127));
        float tp;
        if (d < 256) tp = sinf(ptv * expf(-(float)d * LI255));
        else         tp = cosf(ptv * expf(-(float)(d - 256) * LI255));
        const float v = miv * (gI[(size_t)row * DM + d] + ip)
                      + mtv * (emb[(size_t)tok * DM + d] + tp);
        X[(size_t)row * DM + d] = v;
        Xh[(size_t)row * DM + d] = __float2bfloat16(v);
    }
}

// ---------------------------------------------------------------------------
// LayerNorm over last dim (512), fp32 + bf16 outputs.
// ---------------------------------------------------------------------------
__global__ __launch_bounds__(256) void ln_k(
    const float* __restrict__ in, const float* __restrict__ g,
    const float* __restrict__ b, float* __restrict__ out, bf16* __restrict__ outh)
{
    const int row = blockIdx.x;
    const int tid = threadIdx.x;
    const float* x = in + (size_t)row * DM;
    const float x0 = x[tid], x1 = x[tid + 256];
    __shared__ float red[256];

    red[tid] = x0 + x1;
    __syncthreads();
    for (int off = 128; off > 0; off >>= 1) {
        if (tid < off) red[tid] += red[tid + off];
        __syncthreads();
    }
    const float mean = red[0] / (float)DM;
    __syncthreads();
    const float d0 = x0 - mean, d1 = x1 - mean;
    red[tid] = d0 * d0 + d1 * d1;
    __syncthreads();
    for (int off = 128; off > 0; off >>= 1) {
        if (tid < off) red[tid] += red[tid + off];
        __syncthreads();
    }
    const float var = red[0] / (float)DM;
    const float rstd = rsqrtf(var + 1e-5f);
    const float y0 = d0 * rstd * g[tid] + b[tid];
    const float y1 = d1 * rstd * g[tid + 256] + b[tid + 256];
    out[(size_t)row * DM + tid]        = y0;
    out[(size_t)row * DM + tid + 256]  = y1;
    outh[(size_t)row * DM + tid]       = __float2bfloat16(y0);
    outh[(size_t)row * DM + tid + 256] = __float2bfloat16(y1);
}

// ---------------------------------------------------------------------------
// Linear attention, chunked scan over fused QKV buffer (row stride QS=1536).
// Kp/Vp point at the K / V sub-blocks. State per (n,h): 64x64 KV + 64 ksum.
// ---------------------------------------------------------------------------
__global__ __launch_bounds__(256) void attn_chunk_sum(
    const float* __restrict__ Kp, const float* __restrict__ Vp,
    float* __restrict__ S, float* __restrict__ ks)
{
    const int c = blockIdx.x, h = blockIdx.y, n = blockIdx.z;
    const int tid = threadIdx.x;
    const int e = tid & 63, dq = tid >> 6;
    __shared__ float sK[64], sV[64];
    float s[16] = {};
    float kacc = 0.f;
    for (int l = c * 64; l < c * 64 + 64; ++l) {
        const size_t base = ((size_t)(n * LSEQ + l)) * QS + h * DKH;
        __syncthreads();
        if (tid < 64) {
            const float kv = Kp[base + tid];
            sK[tid] = kv; kacc += kv;
            sV[tid] = Vp[base + tid];
        }
        __syncthreads();
        const float vv = sV[e];
        #pragma unroll
        for (int i = 0; i < 16; ++i) s[i] = fmaf(sK[dq * 16 + i], vv, s[i]);
    }
    const size_t sb = (((size_t)(n * NHEAD + h)) * NCHUNK + c) * 4096;
    #pragma unroll
    for (int i = 0; i < 16; ++i) S[sb + (size_t)(dq * 16 + i) * 64 + e] = s[i];
    if (tid < 64) ks[(((size_t)(n * NHEAD + h)) * NCHUNK + c) * 64 + tid] = kacc;
}

__global__ __launch_bounds__(256) void attn_prefix(
    float* __restrict__ S, float* __restrict__ ks)
{
    const int nh = blockIdx.x;
    const int tid = threadIdx.x;
    float run[16];
    #pragma unroll
    for (int i = 0; i < 16; ++i) run[i] = 0.f;
    float krun = 0.f;
    for (int c = 0; c < NCHUNK; ++c) {
        const size_t sb = (((size_t)nh) * NCHUNK + c) * 4096;
        #pragma unroll
        for (int i = 0; i < 16; ++i) {
            const float t = S[sb + tid * 16 + i];
            S[sb + tid * 16 + i] = run[i];
            run[i] += t;
        }
        if (tid < 64) {
            const size_t kb = (((size_t)nh) * NCHUNK + c) * 64;
            const float t = ks[kb + tid];
            ks[kb + tid] = krun;
            krun += t;
        }
    }
}

__global__ __launch_bounds__(256) void attn_scan(
    const float* __restrict__ Qp, const float* __restrict__ Kp,
    const float* __restrict__ Vp, const float* __restrict__ S,
    const float* __restrict__ ks, bf16* __restrict__ O)
{
    const int c = blockIdx.x, h = blockIdx.y, n = blockIdx.z;
    const int tid = threadIdx.x;
    const int e = tid & 63, dq = tid >> 6;
    __shared__ float sK[64], sV[64], sQ[64], sks[64], part[256];

    const size_t sb = (((size_t)(n * NHEAD + h)) * NCHUNK + c) * 4096;
    float s[16];
    #pragma unroll
    for (int i = 0; i < 16; ++i) s[i] = S[sb + (size_t)(dq * 16 + i) * 64 + e];
    if (tid < 64) sks[tid] = ks[(((size_t)(n * NHEAD + h)) * NCHUNK + c) * 64 + tid];

    for (int l = c * 64; l < c * 64 + 64; ++l) {
        const size_t base = ((size_t)(n * LSEQ + l)) * QS + h * DKH;
        __syncthreads();
        if (tid < 64) {
            sK[tid] = Kp[base + tid];
            sV[tid] = Vp[base + tid];
            sQ[tid] = Qp[base + tid];
        }
        __syncthreads();
        const float vv = sV[e];
        float p = 0.f;
        #pragma unroll
        for (int i = 0; i < 16; ++i) {
            s[i] = fmaf(sK[dq * 16 + i], vv, s[i]);
            p = fmaf(sQ[dq * 16 + i], s[i], p);
        }
        part[tid] = p;
        if (tid < 64) sks[tid] += sK[tid];
        __syncthreads();
        if (tid < 64) {
            const float o = part[tid] + part[tid + 64] + part[tid + 128] + part[tid + 192];
            float zp = sQ[tid] * sks[tid];
            #pragma unroll
            for (int off = 32; off > 0; off >>= 1) zp += __shfl_down(zp, off);
            const float z = __shfl(zp, 0);
            O[((size_t)(n * LSEQ + l)) * DM + h * DKH + tid] =
                __float2bfloat16(o / (z + 1e-6f));
        }
    }
}

// ---------------------------------------------------------------------------
extern "C" void kernel_launch(void* const* d_in, const int* in_sizes, int n_in,
                              void* d_out, int out_size, void* d_ws, size_t ws_size,
                              hipStream_t stream)
{
    const float* x_img   = (const float*)d_in[0];
    const int*   x_txt   = (const int*)  d_in[1];
    const float* mask_i  = (const float*)d_in[2];
    const float* mask_t  = (const float*)d_in[3];
    const float* pos_r   = (const float*)d_in[4];
    const float* pos_c   = (const float*)d_in[5];
    const float* pos_t   = (const float*)d_in[6];
    const float* W_ei    = (const float*)d_in[7];
    const float* b_ei    = (const float*)d_in[8];
    const float* emb_txt = (const float*)d_in[9];
    const float* Wq      = (const float*)d_in[10];
    const float* bq      = (const float*)d_in[11];
    const float* Wk      = (const float*)d_in[12];
    const float* bk      = (const float*)d_in[13];
    const float* Wv      = (const float*)d_in[14];
    const float* bv      = (const float*)d_in[15];
    const float* Wo      = (const float*)d_in[16];
    const float* bo      = (const float*)d_in[17];
    const float* W1      = (const float*)d_in[18];
    const float* b1      = (const float*)d_in[19];
    const float* W2      = (const float*)d_in[20];
    const float* b2      = (const float*)d_in[21];
    const float* ln1_s   = (const float*)d_in[22];
    const float* ln1_b   = (const float*)d_in[23];
    const float* ln2_s   = (const float*)d_in[24];
    const float* ln2_b   = (const float*)d_in[25];
    const float* W_pi    = (const float*)d_in[26];
    const float* b_pi    = (const float*)d_in[27];
    const float* W_pt    = (const float*)d_in[28];
    const float* b_pt    = (const float*)d_in[29];

    float* ws = (float*)d_ws;
    size_t off = 0;
    auto alloc = [&](size_t nfloats) { float* p = ws + off; off += nfloats; return p; };

    float* Xb   = alloc(1048576);           // activations fp32 (N,L,D)
    float* Yb   = alloc(1048576);           // residual-sum scratch
    float* QKVb = alloc(3145728);           // fused QKV fp32 (N,L,1536)
    float* Sb   = alloc(1048576);           // chunk KV prefices
    float* ksb  = alloc(16384);
    float* qkvB = alloc(4 * QS);            // fused bias
    bf16* Xh    = (bf16*)alloc(524288);     // activations bf16
    bf16* Ob    = (bf16*)alloc(524288);     // attention out bf16
    bf16* Tb    = (bf16*)alloc(2097152);    // FF intermediate bf16 (N,L,FF)
    bf16* ximgh = (bf16*)alloc(524288);
    bf16* QKVt  = (bf16*)alloc(1572864);    // (NL,1536,512)
    bf16* Wot   = (bf16*)alloc(524288);     // (NL,512,512)
    bf16* W1t   = (bf16*)alloc(2097152);    // (NL,2048,512)
    bf16* W2t   = (bf16*)alloc(2097152);    // (NL,512,2048)
    bf16* Weit  = (bf16*)alloc(131072);     // (512,512)
    bf16* Wpit  = (bf16*)alloc(131072);     // (512,512)
    bf16* Wptt  = (bf16*)alloc(2064384);    // (8064,512) zero-padded

    const dim3 blk(256);
    const dim3 gAttn(NCHUNK, NHEAD, NB);

    // ---- weight casts (run every launch; ws is re-poisoned) ----
    cast_t<<<dim3(16, 16, 4), blk, 0, stream>>>(Wq, QKVt,            512, 512, 262144, 786432);
    cast_t<<<dim3(16, 16, 4), blk, 0, stream>>>(Wk, QKVt + 262144,   512, 512, 262144, 786432);
    cast_t<<<dim3(16, 16, 4), blk, 0, stream>>>(Wv, QKVt + 524288,   512, 512, 262144, 786432);
    cast_t<<<dim3(16, 16, 4), blk, 0, stream>>>(Wo, Wot,             512, 512, 262144, 262144);
    cast_t<<<dim3(64, 16, 4), blk, 0, stream>>>(W1, W1t,             512, 2048, 1048576, 1048576);
    cast_t<<<dim3(16, 64, 4), blk, 0, stream>>>(W2, W2t,             2048, 512, 1048576, 1048576);
    cast_t<<<dim3(16, 16, 1), blk, 0, stream>>>(W_ei, Weit,          512, 512, 0, 0);
    cast_t<<<dim3(16, 16, 1), blk, 0, stream>>>(W_pi, Wpit,          512, 512, 0, 0);
    cast_t<<<dim3(252, 16, 1), blk, 0, stream>>>(W_pt, Wptt,         512, VOCAB, 0, 0);
    cast_e<<<dim3(1024), blk, 0, stream>>>(x_img, ximgh, 262144);
    qkv_bias_k<<<dim3(4), blk, 0, stream>>>(bq, bk, bv, qkvB);

    // ---- embedding ----
    gemm16<64, 64><<<dim3(8, 32), blk, 0, stream>>>(
        ximgh, Weit, b_ei, nullptr, Yb, nullptr, NROWS, 512, 512, OP_NONE);
    embed_k<<<NROWS, blk, 0, stream>>>(Yb, x_txt, emb_txt, mask_i, mask_t,
                                       pos_r, pos_c, pos_t, Xb, Xh);

    for (int i = 0; i < NLAYER; ++i) {
        // fused QKV projection (elu+1 on Q,K cols)
        gemm16<128, 128><<<dim3(12, 16), blk, 0, stream>>>(
            Xh, QKVt + (size_t)i * 786432, qkvB + i * QS, nullptr,
            QKVb, nullptr, NROWS, 512, QS, OP_QKV);

        attn_chunk_sum<<<gAttn, blk, 0, stream>>>(QKVb + 512, QKVb + 1024, Sb, ksb);
        attn_prefix<<<NB * NHEAD, blk, 0, stream>>>(Sb, ksb);
        attn_scan<<<gAttn, blk, 0, stream>>>(QKVb, QKVb + 512, QKVb + 1024, Sb, ksb, Ob);

        // out proj + residual -> LN1
        gemm16<64, 64><<<dim3(8, 32), blk, 0, stream>>>(
            Ob, Wot + (size_t)i * 262144, bo + (size_t)i * DM, Xb,
            Yb, nullptr, NROWS, 512, 512, OP_NONE);
        ln_k<<<NROWS, blk, 0, stream>>>(Yb, ln1_s + (size_t)i * DM,
                                        ln1_b + (size_t)i * DM, Xb, Xh);

        // FF
        gemm16<128, 128><<<dim3(16, 16), blk, 0, stream>>>(
            Xh, W1t + (size_t)i * 1048576, b1 + (size_t)i * FFD, nullptr,
            nullptr, Tb, NROWS, 512, FFD, OP_GELU);
        gemm16<64, 64><<<dim3(8, 32), blk, 0, stream>>>(
            Tb, W2t + (size_t)i * 1048576, b2 + (size_t)i * DM, Xb,
            Yb, nullptr, NROWS, 2048, 512, OP_NONE);
        ln_k<<<NROWS, blk, 0, stream>>>(Yb, ln2_s + (size_t)i * DM,
                                        ln2_b + (size_t)i * DM, Xb, Xh);
    }

    // ---- heads ----
    float* out = (float*)d_out;
    gemm16<64, 64><<<dim3(8, 32), blk, 0, stream>>>(
        Xh, Wpit, b_pi, nullptr, out, nullptr, NROWS, 512, 512, OP_NONE);
    gemm16<128, 128><<<dim3(63, 16), blk, 0, stream>>>(
        Xh, Wptt, b_pt, nullptr, out + 1048576, nullptr, NROWS, 512, VOCAB, OP_NONE);
}